// Round 2
// baseline (4233.367 us; speedup 1.0000x reference)
//
#include <hip/hip_runtime.h>
#include <cmath>
#include <cstdint>

// HashPINN fused forward: 16-level hash-grid encode + 4-layer MLP, fp32.
// One thread per point; all activations in VGPRs (fully static indexing),
// weights via wave-uniform scalar loads. launch_bounds(256,1) -> VGPR cap 512
// so the allocator never spills (R1 failure mode: 800 MB scratch writes).

#define HASH_SZ (1u << 19)
#define HMASK   (HASH_SZ - 1u)

struct ResArr { int r[16]; };

__global__ __launch_bounds__(256, 1)
void hashpinn_fused(const float* __restrict__ x,
                    const float* __restrict__ table,
                    const float* __restrict__ W1, const float* __restrict__ b1,
                    const float* __restrict__ W2, const float* __restrict__ b2,
                    const float* __restrict__ W3, const float* __restrict__ b3,
                    const float* __restrict__ Wo, const float* __restrict__ bo,
                    float* __restrict__ out, int n, ResArr rv)
{
    const int p = blockIdx.x * 256 + threadIdx.x;
    if (p >= n) return;

    const float px = x[3*p + 0];
    const float py = x[3*p + 1];
    const float pz = x[3*p + 2];

    float feat[32];

    #pragma unroll
    for (int l = 0; l < 16; ++l) {
        const int res = rv.r[l];
        const float rf = (float)(res - 1);
        const float fx = px * rf, fy = py * rf, fz = pz * rf;
        int ix = (int)floorf(fx), iy = (int)floorf(fy), iz = (int)floorf(fz);
        ix = min(max(ix, 0), res - 2);
        iy = min(max(iy, 0), res - 2);
        iz = min(max(iz, 0), res - 2);
        // frac from the CLIPPED integer position (matches reference)
        const float tx = fx - (float)ix, ty = fy - (float)iy, tz = fz - (float)iz;
        const float sx = 1.f - tx, sy = 1.f - ty, sz = 1.f - tz;

        const float2* tbl = (const float2*)table + (size_t)l * HASH_SZ;
        const bool dense = ((long long)res * res * res <= (long long)HASH_SZ);

        // stage all 8 indices, then all 8 loads, then the weighted sum:
        // maximizes loads-in-flight per level.
        uint32_t idx[8];
        #pragma unroll
        for (int c = 0; c < 8; ++c) {
            const uint32_t cx = (uint32_t)(ix + ((c >> 2) & 1));
            const uint32_t cy = (uint32_t)(iy + ((c >> 1) & 1));
            const uint32_t cz = (uint32_t)(iz + (c & 1));
            if (dense) {
                idx[c] = cx + (uint32_t)res * (cy + (uint32_t)res * cz);
            } else {
                idx[c] = (cx * 1u ^ cy * 2654435761u ^ cz * 805459861u) & HMASK;
            }
        }
        float2 v[8];
        #pragma unroll
        for (int c = 0; c < 8; ++c) v[c] = tbl[idx[c]];

        float a0 = 0.f, a1 = 0.f;
        #pragma unroll
        for (int c = 0; c < 8; ++c) {
            const float wx = ((c >> 2) & 1) ? tx : sx;
            const float wy = ((c >> 1) & 1) ? ty : sy;
            const float wz = (c & 1) ? tz : sz;
            const float w = wx * wy * wz;
            a0 = fmaf(w, v[c].x, a0);
            a1 = fmaf(w, v[c].y, a1);
        }
        feat[2*l + 0] = a0;
        feat[2*l + 1] = a1;
    }

    // ---- MLP: 32 -> 64 -> 64 -> 64 -> 1, fp32 vector ALU, straight-line ----
    float A[64], B[64];

    // layer 1: A = feat @ W1 + b1
    #pragma unroll
    for (int j = 0; j < 64; ++j) A[j] = b1[j];
    #pragma unroll
    for (int k = 0; k < 32; ++k) {
        const float h = feat[k];
        #pragma unroll
        for (int j = 0; j < 64; ++j) A[j] = fmaf(h, W1[k*64 + j], A[j]);
    }

    // layer 2: B = relu(A) @ W2 + b2
    #pragma unroll
    for (int j = 0; j < 64; ++j) B[j] = b2[j];
    #pragma unroll
    for (int k = 0; k < 64; ++k) {
        const float h = fmaxf(A[k], 0.f);
        #pragma unroll
        for (int j = 0; j < 64; ++j) B[j] = fmaf(h, W2[k*64 + j], B[j]);
    }

    // layer 3: A = relu(B) @ W3 + b3
    #pragma unroll
    for (int j = 0; j < 64; ++j) A[j] = b3[j];
    #pragma unroll
    for (int k = 0; k < 64; ++k) {
        const float h = fmaxf(B[k], 0.f);
        #pragma unroll
        for (int j = 0; j < 64; ++j) A[j] = fmaf(h, W3[k*64 + j], A[j]);
    }

    // output: o = relu(A) @ Wo + bo
    float o = bo[0];
    #pragma unroll
    for (int j = 0; j < 64; ++j) o = fmaf(fmaxf(A[j], 0.f), Wo[j], o);

    out[p] = o;
}

extern "C" void kernel_launch(void* const* d_in, const int* in_sizes, int n_in,
                              void* d_out, int out_size, void* d_ws, size_t ws_size,
                              hipStream_t stream) {
    const float* x     = (const float*)d_in[0];
    const float* table = (const float*)d_in[1];
    const float* W1    = (const float*)d_in[2];
    const float* b1    = (const float*)d_in[3];
    const float* W2    = (const float*)d_in[4];
    const float* b2    = (const float*)d_in[5];
    const float* W3    = (const float*)d_in[6];
    const float* b3    = (const float*)d_in[7];
    const float* Wo    = (const float*)d_in[8];
    const float* bo    = (const float*)d_in[9];
    float* out = (float*)d_out;

    const int n = in_sizes[0] / 3;

    // Replicate numpy's resolution computation with host libm:
    // scale = exp2(log2(2048/16)/15); res_l = int(ceil(16 * scale**l))
    ResArr rv;
    const double scale = std::exp2(std::log2(2048.0 / 16.0) / 15.0);
    for (int l = 0; l < 16; ++l)
        rv.r[l] = (int)std::ceil(16.0 * std::pow(scale, (double)l));

    const int blocks = (n + 255) / 256;
    hipLaunchKernelGGL(hashpinn_fused, dim3(blocks), dim3(256), 0, stream,
                       x, table, W1, b1, W2, b2, W3, b3, Wo, bo, out, n, rv);
}

// Round 3
// 2170.514 us; speedup vs baseline: 1.9504x; 1.9504x over previous
//
#include <hip/hip_runtime.h>
#include <cmath>
#include <cstdint>

// HashPINN split pipeline:
//  K1 encode_phased: persistent grid, level-major loops -> all resident waves
//     gather from the SAME 4MB table at once (fits per-XCD L2). High occupancy
//     (launch_bounds(256,8), ~40 VGPR) for gather-latency hiding.
//     Writes features transposed [32][N] to d_ws (coalesced dword streams).
//  K2 mlp_forward: one thread/point, straight-line fp32 VALU MLP (no spills,
//     verified R2: WRITE_SIZE ~= out only).

#define HASH_SZ (1u << 19)
#define HMASK   (HASH_SZ - 1u)

struct ResArr { int r[16]; };

__global__ __launch_bounds__(256, 8)
void encode_phased(const float* __restrict__ x,
                   const float* __restrict__ table,
                   float* __restrict__ featT,   // [32][n]
                   int n, ResArr rv)
{
    const int nth = gridDim.x * 256;
    const int t0  = blockIdx.x * 256 + threadIdx.x;

    #pragma unroll 1
    for (int l = 0; l < 16; ++l) {
        const int res = rv.r[l];
        const float rf = (float)(res - 1);
        const float2* __restrict__ tbl = (const float2*)table + (size_t)l * HASH_SZ;
        const bool dense = ((long long)res * res * res <= (long long)HASH_SZ);
        float* __restrict__ o0 = featT + (size_t)(2*l)     * n;
        float* __restrict__ o1 = featT + (size_t)(2*l + 1) * n;

        #pragma unroll 1
        for (int p = t0; p < n; p += nth) {
            const float px = x[3*p + 0];
            const float py = x[3*p + 1];
            const float pz = x[3*p + 2];
            const float fx = px * rf, fy = py * rf, fz = pz * rf;
            int ix = (int)floorf(fx), iy = (int)floorf(fy), iz = (int)floorf(fz);
            ix = min(max(ix, 0), res - 2);
            iy = min(max(iy, 0), res - 2);
            iz = min(max(iz, 0), res - 2);
            const float tx = fx - (float)ix, ty = fy - (float)iy, tz = fz - (float)iz;
            const float sx = 1.f - tx, sy = 1.f - ty, sz = 1.f - tz;

            uint32_t idx[8];
            #pragma unroll
            for (int c = 0; c < 8; ++c) {
                const uint32_t cx = (uint32_t)(ix + ((c >> 2) & 1));
                const uint32_t cy = (uint32_t)(iy + ((c >> 1) & 1));
                const uint32_t cz = (uint32_t)(iz + (c & 1));
                if (dense) {  // wave-uniform branch (res uniform per level)
                    idx[c] = cx + (uint32_t)res * (cy + (uint32_t)res * cz);
                } else {
                    idx[c] = (cx * 1u ^ cy * 2654435761u ^ cz * 805459861u) & HMASK;
                }
            }
            float2 v[8];
            #pragma unroll
            for (int c = 0; c < 8; ++c) v[c] = tbl[idx[c]];

            float a0 = 0.f, a1 = 0.f;
            #pragma unroll
            for (int c = 0; c < 8; ++c) {
                const float wx = ((c >> 2) & 1) ? tx : sx;
                const float wy = ((c >> 1) & 1) ? ty : sy;
                const float wz = (c & 1) ? tz : sz;
                const float w = wx * wy * wz;
                a0 = fmaf(w, v[c].x, a0);
                a1 = fmaf(w, v[c].y, a1);
            }
            o0[p] = a0;
            o1[p] = a1;
        }
    }
}

__global__ __launch_bounds__(256, 1)
void mlp_forward(const float* __restrict__ featT,
                 const float* __restrict__ W1, const float* __restrict__ b1,
                 const float* __restrict__ W2, const float* __restrict__ b2,
                 const float* __restrict__ W3, const float* __restrict__ b3,
                 const float* __restrict__ Wo, const float* __restrict__ bo,
                 float* __restrict__ out, int n)
{
    const int p = blockIdx.x * 256 + threadIdx.x;
    if (p >= n) return;

    float A[64], B[64];

    #pragma unroll
    for (int j = 0; j < 64; ++j) A[j] = b1[j];
    #pragma unroll
    for (int k = 0; k < 32; ++k) {
        const float h = featT[(size_t)k * n + p];
        #pragma unroll
        for (int j = 0; j < 64; ++j) A[j] = fmaf(h, W1[k*64 + j], A[j]);
    }

    #pragma unroll
    for (int j = 0; j < 64; ++j) B[j] = b2[j];
    #pragma unroll
    for (int k = 0; k < 64; ++k) {
        const float h = fmaxf(A[k], 0.f);
        #pragma unroll
        for (int j = 0; j < 64; ++j) B[j] = fmaf(h, W2[k*64 + j], B[j]);
    }

    #pragma unroll
    for (int j = 0; j < 64; ++j) A[j] = b3[j];
    #pragma unroll
    for (int k = 0; k < 64; ++k) {
        const float h = fmaxf(B[k], 0.f);
        #pragma unroll
        for (int j = 0; j < 64; ++j) A[j] = fmaf(h, W3[k*64 + j], A[j]);
    }

    float o = bo[0];
    #pragma unroll
    for (int j = 0; j < 64; ++j) o = fmaf(fmaxf(A[j], 0.f), Wo[j], o);

    out[p] = o;
}

// Fallback (ws too small): R1 fused kernel.
__global__ __launch_bounds__(256, 2)
void hashpinn_fused(const float* __restrict__ x,
                    const float* __restrict__ table,
                    const float* __restrict__ W1, const float* __restrict__ b1,
                    const float* __restrict__ W2, const float* __restrict__ b2,
                    const float* __restrict__ W3, const float* __restrict__ b3,
                    const float* __restrict__ Wo, const float* __restrict__ bo,
                    float* __restrict__ out, int n, ResArr rv)
{
    const int p = blockIdx.x * 256 + threadIdx.x;
    if (p >= n) return;
    const float px = x[3*p+0], py = x[3*p+1], pz = x[3*p+2];
    float feat[32];
    #pragma unroll
    for (int l = 0; l < 16; ++l) {
        const int res = rv.r[l];
        const float rf = (float)(res - 1);
        const float fx = px*rf, fy = py*rf, fz = pz*rf;
        int ix=(int)floorf(fx), iy=(int)floorf(fy), iz=(int)floorf(fz);
        ix=min(max(ix,0),res-2); iy=min(max(iy,0),res-2); iz=min(max(iz,0),res-2);
        const float tx=fx-(float)ix, ty=fy-(float)iy, tz=fz-(float)iz;
        const float sx=1.f-tx, sy=1.f-ty, sz=1.f-tz;
        const float2* tbl=(const float2*)table+(size_t)l*HASH_SZ;
        const bool dense=((long long)res*res*res<=(long long)HASH_SZ);
        float a0=0.f, a1=0.f;
        #pragma unroll
        for (int c=0;c<8;++c){
            const uint32_t cx=(uint32_t)(ix+((c>>2)&1));
            const uint32_t cy=(uint32_t)(iy+((c>>1)&1));
            const uint32_t cz=(uint32_t)(iz+(c&1));
            uint32_t idx = dense ? cx+(uint32_t)res*(cy+(uint32_t)res*cz)
                                 : ((cx*1u ^ cy*2654435761u ^ cz*805459861u)&HMASK);
            const float2 v=tbl[idx];
            const float w=(((c>>2)&1)?tx:sx)*(((c>>1)&1)?ty:sy)*((c&1)?tz:sz);
            a0=fmaf(w,v.x,a0); a1=fmaf(w,v.y,a1);
        }
        feat[2*l]=a0; feat[2*l+1]=a1;
    }
    float A[64], B[64];
    #pragma unroll
    for (int j=0;j<64;++j) A[j]=b1[j];
    #pragma unroll
    for (int k=0;k<32;++k){ const float h=feat[k];
        #pragma unroll
        for (int j=0;j<64;++j) A[j]=fmaf(h,W1[k*64+j],A[j]); }
    #pragma unroll 1
    for (int it=0;it<2;++it){
        const float* W = it?W3:W2; const float* bb = it?b3:b2;
        #pragma unroll
        for (int j=0;j<64;++j){ A[j]=fmaxf(A[j],0.f); B[j]=bb[j]; }
        #pragma unroll
        for (int k=0;k<64;++k){ const float h=A[k];
            #pragma unroll
            for (int j=0;j<64;++j) B[j]=fmaf(h,W[k*64+j],B[j]); }
        #pragma unroll
        for (int j=0;j<64;++j) A[j]=B[j];
    }
    float o=bo[0];
    #pragma unroll
    for (int j=0;j<64;++j) o=fmaf(fmaxf(A[j],0.f),Wo[j],o);
    out[p]=o;
}

extern "C" void kernel_launch(void* const* d_in, const int* in_sizes, int n_in,
                              void* d_out, int out_size, void* d_ws, size_t ws_size,
                              hipStream_t stream) {
    const float* x     = (const float*)d_in[0];
    const float* table = (const float*)d_in[1];
    const float* W1    = (const float*)d_in[2];
    const float* b1    = (const float*)d_in[3];
    const float* W2    = (const float*)d_in[4];
    const float* b2    = (const float*)d_in[5];
    const float* W3    = (const float*)d_in[6];
    const float* b3    = (const float*)d_in[7];
    const float* Wo    = (const float*)d_in[8];
    const float* bo    = (const float*)d_in[9];
    float* out = (float*)d_out;

    const int n = in_sizes[0] / 3;

    // numpy-matching resolutions via host libm
    ResArr rv;
    const double scale = std::exp2(std::log2(2048.0 / 16.0) / 15.0);
    for (int l = 0; l < 16; ++l)
        rv.r[l] = (int)std::ceil(16.0 * std::pow(scale, (double)l));

    const size_t feat_bytes = (size_t)n * 32 * sizeof(float);

    if (ws_size >= feat_bytes) {
        float* featT = (float*)d_ws;
        // persistent-ish grid: 8 blocks/CU x 256 CUs resident -> level lockstep
        hipLaunchKernelGGL(encode_phased, dim3(2048), dim3(256), 0, stream,
                           x, table, featT, n, rv);
        hipLaunchKernelGGL(mlp_forward, dim3((n + 255) / 256), dim3(256), 0, stream,
                           featT, W1, b1, W2, b2, W3, b3, Wo, bo, out, n);
    } else {
        hipLaunchKernelGGL(hashpinn_fused, dim3((n + 255) / 256), dim3(256), 0, stream,
                           x, table, W1, b1, W2, b2, W3, b3, Wo, bo, out, n, rv);
    }
}

// Round 4
// 1661.875 us; speedup vs baseline: 2.5473x; 1.3061x over previous
//
#include <hip/hip_runtime.h>
#include <cmath>
#include <cstdint>

// HashPINN split pipeline, R4:
//  - encode_levels launched once per PHASE (dense levels merged, each hashed
//    level its own dispatch). Stream serialization = hard lockstep barrier,
//    so each XCD's L2 holds exactly one 4MB table during a hashed phase.
//  - nontemporal loads/stores on all streaming traffic (x, featT, out) to
//    keep L2 capacity for table gather lines.
//  - MLP: launch_bounds(256,3); layer3+output fused in j-halves to keep
//    peak live VGPRs ~140 (fits the 170 cap, no scratch).

#define HASH_SZ (1u << 19)
#define HMASK   (HASH_SZ - 1u)

struct ResArr { int r[16]; };

__global__ __launch_bounds__(256, 8)
void encode_levels(const float* __restrict__ x,
                   const float* __restrict__ table,
                   float* __restrict__ featT,   // [32][n]
                   int n, int lb, int le, ResArr rv)
{
    const int nth = gridDim.x * 256;
    const int t0  = blockIdx.x * 256 + threadIdx.x;

    #pragma unroll 1
    for (int p = t0; p < n; p += nth) {
        const float px = __builtin_nontemporal_load(&x[3*p + 0]);
        const float py = __builtin_nontemporal_load(&x[3*p + 1]);
        const float pz = __builtin_nontemporal_load(&x[3*p + 2]);

        #pragma unroll 1
        for (int l = lb; l < le; ++l) {
            const int res = rv.r[l];
            const float rf = (float)(res - 1);
            const float2* __restrict__ tbl = (const float2*)table + (size_t)l * HASH_SZ;
            const bool dense = ((long long)res * res * res <= (long long)HASH_SZ);

            const float fx = px * rf, fy = py * rf, fz = pz * rf;
            int ix = (int)floorf(fx), iy = (int)floorf(fy), iz = (int)floorf(fz);
            ix = min(max(ix, 0), res - 2);
            iy = min(max(iy, 0), res - 2);
            iz = min(max(iz, 0), res - 2);
            const float tx = fx - (float)ix, ty = fy - (float)iy, tz = fz - (float)iz;
            const float sx = 1.f - tx, sy = 1.f - ty, sz = 1.f - tz;

            uint32_t idx[8];
            #pragma unroll
            for (int c = 0; c < 8; ++c) {
                const uint32_t cx = (uint32_t)(ix + ((c >> 2) & 1));
                const uint32_t cy = (uint32_t)(iy + ((c >> 1) & 1));
                const uint32_t cz = (uint32_t)(iz + (c & 1));
                if (dense) {  // wave-uniform (res uniform per level)
                    idx[c] = cx + (uint32_t)res * (cy + (uint32_t)res * cz);
                } else {
                    idx[c] = (cx * 1u ^ cy * 2654435761u ^ cz * 805459861u) & HMASK;
                }
            }
            float2 v[8];
            #pragma unroll
            for (int c = 0; c < 8; ++c) v[c] = tbl[idx[c]];

            float a0 = 0.f, a1 = 0.f;
            #pragma unroll
            for (int c = 0; c < 8; ++c) {
                const float wx = ((c >> 2) & 1) ? tx : sx;
                const float wy = ((c >> 1) & 1) ? ty : sy;
                const float wz = (c & 1) ? tz : sz;
                const float w = wx * wy * wz;
                a0 = fmaf(w, v[c].x, a0);
                a1 = fmaf(w, v[c].y, a1);
            }
            __builtin_nontemporal_store(a0, &featT[(size_t)(2*l)     * n + p]);
            __builtin_nontemporal_store(a1, &featT[(size_t)(2*l + 1) * n + p]);
        }
    }
}

__global__ __launch_bounds__(256, 3)
void mlp_forward(const float* __restrict__ featT,
                 const float* __restrict__ W1, const float* __restrict__ b1,
                 const float* __restrict__ W2, const float* __restrict__ b2,
                 const float* __restrict__ W3, const float* __restrict__ b3,
                 const float* __restrict__ Wo, const float* __restrict__ bo,
                 float* __restrict__ out, int n)
{
    const int p = blockIdx.x * 256 + threadIdx.x;
    if (p >= n) return;

    float A[64], B[64];

    // layer 1: A = feat @ W1 + b1   (feat streamed from global, nt)
    #pragma unroll
    for (int j = 0; j < 64; ++j) A[j] = b1[j];
    #pragma unroll
    for (int k = 0; k < 32; ++k) {
        const float h = __builtin_nontemporal_load(&featT[(size_t)k * n + p]);
        #pragma unroll
        for (int j = 0; j < 64; ++j) A[j] = fmaf(h, W1[k*64 + j], A[j]);
    }

    // layer 2: B = relu(A) @ W2 + b2
    #pragma unroll
    for (int j = 0; j < 64; ++j) B[j] = b2[j];
    #pragma unroll
    for (int k = 0; k < 64; ++k) {
        const float h = fmaxf(A[k], 0.f);
        #pragma unroll
        for (int j = 0; j < 64; ++j) B[j] = fmaf(h, W2[k*64 + j], B[j]);
    }

    // layer 3 + output, fused in j-halves: keeps live regs = B[64]+C[32]+o
    float o = bo[0];
    #pragma unroll 1
    for (int h2 = 0; h2 < 2; ++h2) {
        const int j0 = h2 * 32;
        float C[32];
        #pragma unroll
        for (int j = 0; j < 32; ++j) C[j] = b3[j0 + j];
        #pragma unroll
        for (int k = 0; k < 64; ++k) {
            const float h = fmaxf(B[k], 0.f);
            #pragma unroll
            for (int j = 0; j < 32; ++j) C[j] = fmaf(h, W3[k*64 + j0 + j], C[j]);
        }
        #pragma unroll
        for (int j = 0; j < 32; ++j) o = fmaf(fmaxf(C[j], 0.f), Wo[j0 + j], o);
    }

    out[p] = o;
}

// Fallback (ws too small): R1-style fused kernel.
__global__ __launch_bounds__(256, 2)
void hashpinn_fused(const float* __restrict__ x,
                    const float* __restrict__ table,
                    const float* __restrict__ W1, const float* __restrict__ b1,
                    const float* __restrict__ W2, const float* __restrict__ b2,
                    const float* __restrict__ W3, const float* __restrict__ b3,
                    const float* __restrict__ Wo, const float* __restrict__ bo,
                    float* __restrict__ out, int n, ResArr rv)
{
    const int p = blockIdx.x * 256 + threadIdx.x;
    if (p >= n) return;
    const float px = x[3*p+0], py = x[3*p+1], pz = x[3*p+2];
    float feat[32];
    #pragma unroll
    for (int l = 0; l < 16; ++l) {
        const int res = rv.r[l];
        const float rf = (float)(res - 1);
        const float fx = px*rf, fy = py*rf, fz = pz*rf;
        int ix=(int)floorf(fx), iy=(int)floorf(fy), iz=(int)floorf(fz);
        ix=min(max(ix,0),res-2); iy=min(max(iy,0),res-2); iz=min(max(iz,0),res-2);
        const float tx=fx-(float)ix, ty=fy-(float)iy, tz=fz-(float)iz;
        const float sx=1.f-tx, sy=1.f-ty, sz=1.f-tz;
        const float2* tbl=(const float2*)table+(size_t)l*HASH_SZ;
        const bool dense=((long long)res*res*res<=(long long)HASH_SZ);
        float a0=0.f, a1=0.f;
        #pragma unroll
        for (int c=0;c<8;++c){
            const uint32_t cx=(uint32_t)(ix+((c>>2)&1));
            const uint32_t cy=(uint32_t)(iy+((c>>1)&1));
            const uint32_t cz=(uint32_t)(iz+(c&1));
            uint32_t idx = dense ? cx+(uint32_t)res*(cy+(uint32_t)res*cz)
                                 : ((cx*1u ^ cy*2654435761u ^ cz*805459861u)&HMASK);
            const float2 v=tbl[idx];
            const float w=(((c>>2)&1)?tx:sx)*(((c>>1)&1)?ty:sy)*((c&1)?tz:sz);
            a0=fmaf(w,v.x,a0); a1=fmaf(w,v.y,a1);
        }
        feat[2*l]=a0; feat[2*l+1]=a1;
    }
    float A[64], B[64];
    #pragma unroll
    for (int j=0;j<64;++j) A[j]=b1[j];
    #pragma unroll
    for (int k=0;k<32;++k){ const float h=feat[k];
        #pragma unroll
        for (int j=0;j<64;++j) A[j]=fmaf(h,W1[k*64+j],A[j]); }
    #pragma unroll 1
    for (int it=0;it<2;++it){
        const float* W = it?W3:W2; const float* bb = it?b3:b2;
        #pragma unroll
        for (int j=0;j<64;++j){ A[j]=fmaxf(A[j],0.f); B[j]=bb[j]; }
        #pragma unroll
        for (int k=0;k<64;++k){ const float h=A[k];
            #pragma unroll
            for (int j=0;j<64;++j) B[j]=fmaf(h,W[k*64+j],B[j]); }
        #pragma unroll
        for (int j=0;j<64;++j) A[j]=B[j];
    }
    float o=bo[0];
    #pragma unroll
    for (int j=0;j<64;++j) o=fmaf(fmaxf(A[j],0.f),Wo[j],o);
    out[p]=o;
}

extern "C" void kernel_launch(void* const* d_in, const int* in_sizes, int n_in,
                              void* d_out, int out_size, void* d_ws, size_t ws_size,
                              hipStream_t stream) {
    const float* x     = (const float*)d_in[0];
    const float* table = (const float*)d_in[1];
    const float* W1    = (const float*)d_in[2];
    const float* b1    = (const float*)d_in[3];
    const float* W2    = (const float*)d_in[4];
    const float* b2    = (const float*)d_in[5];
    const float* W3    = (const float*)d_in[6];
    const float* b3    = (const float*)d_in[7];
    const float* Wo    = (const float*)d_in[8];
    const float* bo    = (const float*)d_in[9];
    float* out = (float*)d_out;

    const int n = in_sizes[0] / 3;

    // numpy-matching resolutions via host libm
    ResArr rv;
    const double scale = std::exp2(std::log2(2048.0 / 16.0) / 15.0);
    for (int l = 0; l < 16; ++l)
        rv.r[l] = (int)std::ceil(16.0 * std::pow(scale, (double)l));

    // dense prefix: levels with res^3 <= HASH_SZ (tables sum < 4MB L2)
    int dense_end = 0;
    while (dense_end < 16) {
        long long r = rv.r[dense_end];
        if (r * r * r <= (long long)HASH_SZ) ++dense_end; else break;
    }

    const size_t feat_bytes = (size_t)n * 32 * sizeof(float);

    if (ws_size >= feat_bytes) {
        float* featT = (float*)d_ws;
        const dim3 eg(4096), eb(256);
        // phase 0: all dense levels in one sweep (combined tables fit L2)
        if (dense_end > 0)
            hipLaunchKernelGGL(encode_levels, eg, eb, 0, stream,
                               x, table, featT, n, 0, dense_end, rv);
        // one dispatch per hashed level: stream order = hard phase barrier
        for (int l = dense_end; l < 16; ++l)
            hipLaunchKernelGGL(encode_levels, eg, eb, 0, stream,
                               x, table, featT, n, l, l + 1, rv);

        hipLaunchKernelGGL(mlp_forward, dim3((n + 255) / 256), dim3(256), 0, stream,
                           featT, W1, b1, W2, b2, W3, b3, Wo, bo, out, n);
    } else {
        hipLaunchKernelGGL(hashpinn_fused, dim3((n + 255) / 256), dim3(256), 0, stream,
                           x, table, W1, b1, W2, b2, W3, b3, Wo, bo, out, n, rv);
    }
}